// Round 1
// baseline (1866.540 us; speedup 1.0000x reference)
//
#include <hip/hip_runtime.h>
#include <math.h>

// Problem constants: B=8, C=64, T=128, E=256, 4E=1024, TYPE_NUM=40, NF=128
// Decomposition: h_pre[b,c,t,:] = Apre[c,:] + Bmat[b*T+t,:] + W34 @ [|q-ctx|; q*ctx]
//   Apre = q @ W1^T + b_hidden   (W1 = W_hidden[:,0:256])
//   Bmat = ctx @ W2^T            (W2 = W_hidden[:,256:512])
//   W34  = W_hidden[:,512:1024]  (pair terms, K=512)
// Big kernel fuses: pair-GEMM (M=128 t, N=1024, K=512 per (b,c) block),
// tanh, dot with W_v, mask, softmax over t, and g = attn @ ctx.

// ---------------- generic fp32 tiled GEMM: C = act(A @ B^T + bias) ----------------
// A [M,K] lda, B [N,K] ldb (row-major N x K), C [M,N] ldc.
// Requires M,N multiples of 64 and K multiple of 16 (all shapes here comply).
__global__ __launch_bounds__(256) void gemm_tn_kernel(
    const float* __restrict__ A, int lda,
    const float* __restrict__ B, int ldb,
    const float* __restrict__ bias,
    float* __restrict__ C, int ldc,
    int K, int act)
{
    __shared__ float As[16][68];
    __shared__ float Bs[16][68];
    const int tid = threadIdx.x;
    const int m0 = blockIdx.y * 64, n0 = blockIdx.x * 64;
    const int tm = tid >> 4, tn = tid & 15;
    const int lr = tid >> 2;        // 0..63: tile row loaded by this thread
    const int lc = (tid & 3) * 4;   // 0,4,8,12: k-offset

    float acc[4][4];
#pragma unroll
    for (int i = 0; i < 4; ++i)
#pragma unroll
        for (int j = 0; j < 4; ++j) acc[i][j] = 0.f;

    for (int k0 = 0; k0 < K; k0 += 16) {
        float4 av = *reinterpret_cast<const float4*>(A + (size_t)(m0 + lr) * lda + k0 + lc);
        float4 bv = *reinterpret_cast<const float4*>(B + (size_t)(n0 + lr) * ldb + k0 + lc);
        As[lc + 0][lr] = av.x; As[lc + 1][lr] = av.y; As[lc + 2][lr] = av.z; As[lc + 3][lr] = av.w;
        Bs[lc + 0][lr] = bv.x; Bs[lc + 1][lr] = bv.y; Bs[lc + 2][lr] = bv.z; Bs[lc + 3][lr] = bv.w;
        __syncthreads();
#pragma unroll
        for (int kk = 0; kk < 16; ++kk) {
            float4 a = *reinterpret_cast<const float4*>(&As[kk][tm * 4]);
            float4 b = *reinterpret_cast<const float4*>(&Bs[kk][tn * 4]);
            float ar[4] = {a.x, a.y, a.z, a.w};
            float br[4] = {b.x, b.y, b.z, b.w};
#pragma unroll
            for (int i = 0; i < 4; ++i)
#pragma unroll
                for (int j = 0; j < 4; ++j) acc[i][j] += ar[i] * br[j];
        }
        __syncthreads();
    }

#pragma unroll
    for (int i = 0; i < 4; ++i) {
        int m = m0 + tm * 4 + i;
        float vals[4];
#pragma unroll
        for (int j = 0; j < 4; ++j) {
            int n = n0 + tn * 4 + j;
            float v = acc[i][j];
            if (bias) v += bias[n];
            if (act) v = tanhf(v);
            vals[j] = v;
        }
        float4 o; o.x = vals[0]; o.y = vals[1]; o.z = vals[2]; o.w = vals[3];
        *reinterpret_cast<float4*>(C + (size_t)m * ldc + n0 + tn * 4) = o;
    }
}

// ---------------- fused pair-GEMM + tanh + W_v dot + softmax + g ----------------
// One block per (b,c). 256 threads. Tile: 128 t x 128 j per N-chunk, K=512.
__global__ __launch_bounds__(256) void attn_kernel(
    const float* __restrict__ q,     // [64][256]
    const float* __restrict__ ctx,   // [8][128][256]
    const int*   __restrict__ mask,  // [8][128]
    const float* __restrict__ Wh,    // [1024][1024]
    const float* __restrict__ Wv,    // [1024]
    const float* __restrict__ bv,    // [1]
    const float* __restrict__ Apre,  // [64][1024]  (includes b_hidden)
    const float* __restrict__ Bmat,  // [1024][1024]
    float* __restrict__ g)           // [512][256]
{
    __shared__ float qc[256];
    __shared__ float Us[16][132];   // [k][t], padded
    __shared__ float Ws[16][132];   // [k][j], padded
    __shared__ float sc[128];
    __shared__ float red;

    const int tid = threadIdx.x;
    const int b = blockIdx.x >> 6, c = blockIdx.x & 63;
    const int tj = tid & 15, tt = tid >> 4;
    const int sr = tid >> 1;          // staging row 0..127
    const int s8 = (tid & 1) * 8;     // staging k-offset 0/8

    qc[tid] = q[c * 256 + tid];
    if (tid < 128) sc[tid] = 0.f;
    __syncthreads();

    for (int nc = 0; nc < 8; ++nc) {
        float acc[8][8];
#pragma unroll
        for (int i = 0; i < 8; ++i)
#pragma unroll
            for (int j = 0; j < 8; ++j) acc[i][j] = 0.f;

        for (int k0 = 0; k0 < 512; k0 += 16) {
            // stage W34 tile: Ws[kk][jj] = Wh[nc*128+jj][512+k0+kk]
            const float* wp = Wh + (size_t)(nc * 128 + sr) * 1024 + 512 + k0 + s8;
            float4 w0 = *reinterpret_cast<const float4*>(wp);
            float4 w1 = *reinterpret_cast<const float4*>(wp + 4);
            Ws[s8 + 0][sr] = w0.x; Ws[s8 + 1][sr] = w0.y; Ws[s8 + 2][sr] = w0.z; Ws[s8 + 3][sr] = w0.w;
            Ws[s8 + 4][sr] = w1.x; Ws[s8 + 5][sr] = w1.y; Ws[s8 + 6][sr] = w1.z; Ws[s8 + 7][sr] = w1.w;
            // stage U tile: k<256 -> |q-ctx|, k>=256 -> q*ctx (same e index mod 256)
            const int e0 = (k0 & 255) + s8;
            const float* cp = ctx + (size_t)(b * 128 + sr) * 256 + e0;
            float4 c0 = *reinterpret_cast<const float4*>(cp);
            float4 c1 = *reinterpret_cast<const float4*>(cp + 4);
            float cv[8] = {c0.x, c0.y, c0.z, c0.w, c1.x, c1.y, c1.z, c1.w};
            if (k0 < 256) {
#pragma unroll
                for (int ii = 0; ii < 8; ++ii) Us[s8 + ii][sr] = fabsf(qc[e0 + ii] - cv[ii]);
            } else {
#pragma unroll
                for (int ii = 0; ii < 8; ++ii) Us[s8 + ii][sr] = qc[e0 + ii] * cv[ii];
            }
            __syncthreads();
#pragma unroll
            for (int kk = 0; kk < 16; ++kk) {
                float4 a0 = *reinterpret_cast<const float4*>(&Us[kk][tt * 8]);
                float4 a1 = *reinterpret_cast<const float4*>(&Us[kk][tt * 8 + 4]);
                float4 b0 = *reinterpret_cast<const float4*>(&Ws[kk][tj * 8]);
                float4 b1 = *reinterpret_cast<const float4*>(&Ws[kk][tj * 8 + 4]);
                float ar[8] = {a0.x, a0.y, a0.z, a0.w, a1.x, a1.y, a1.z, a1.w};
                float br[8] = {b0.x, b0.y, b0.z, b0.w, b1.x, b1.y, b1.z, b1.w};
#pragma unroll
                for (int i = 0; i < 8; ++i)
#pragma unroll
                    for (int j = 0; j < 8; ++j) acc[i][j] += ar[i] * br[j];
            }
            __syncthreads();
        }

        // epilogue: h = tanh(acc + Apre + Bmat), partial score = h . Wv
        const int colb = nc * 128 + tj * 8;
        float av[8], wv[8];
#pragma unroll
        for (int j = 0; j < 8; ++j) { av[j] = Apre[c * 1024 + colb + j]; wv[j] = Wv[colb + j]; }
#pragma unroll
        for (int i = 0; i < 8; ++i) {
            const int t = tt * 8 + i;
            const float* bm = Bmat + (size_t)(b * 128 + t) * 1024 + colb;
            float p = 0.f;
#pragma unroll
            for (int j = 0; j < 8; ++j) p += tanhf(acc[i][j] + av[j] + bm[j]) * wv[j];
            p += __shfl_xor(p, 1, 16);
            p += __shfl_xor(p, 2, 16);
            p += __shfl_xor(p, 4, 16);
            p += __shfl_xor(p, 8, 16);
            if (tj == 0) sc[t] += p;   // same thread owns t across all nc -> no race
        }
    }
    __syncthreads();

    // mask + b_v, then softmax over t
    if (tid < 128) {
        float s = sc[tid] + bv[0];
        if (mask[b * 128 + tid] < 1) s = -1e10f;
        sc[tid] = s;
    }
    __syncthreads();
    if (tid < 64) {
        float m = fmaxf(sc[tid], sc[tid + 64]);
        for (int off = 32; off; off >>= 1) m = fmaxf(m, __shfl_xor(m, off, 64));
        if (tid == 0) red = m;
    }
    __syncthreads();
    const float mx = red;
    if (tid < 128) sc[tid] = expf(sc[tid] - mx);
    __syncthreads();
    if (tid < 64) {
        float s = sc[tid] + sc[tid + 64];
        for (int off = 32; off; off >>= 1) s += __shfl_xor(s, off, 64);
        if (tid == 0) red = s;
    }
    __syncthreads();
    const float inv = 1.f / red;

    // g[b,c,e] = sum_t attn[t] * ctx[b,t,e]; lane e = tid, coalesced per t
    float gv = 0.f;
    for (int t = 0; t < 128; ++t) gv += sc[t] * ctx[(size_t)(b * 128 + t) * 256 + tid];
    g[(size_t)blockIdx.x * 256 + tid] = gv * inv;
}

// ---------------- build feat2 = [q, g, |q-g|, q*g] for the h2 GEMM ----------------
__global__ void feat2_kernel(const float* __restrict__ q, const float* __restrict__ g,
                             float* __restrict__ feat2)
{
    int idx = blockIdx.x * 256 + threadIdx.x;  // < 512*1024
    int row = idx >> 10, col = idx & 1023;
    int c = row & 63;
    int e = col & 255, sel = col >> 8;
    float qv = q[c * 256 + e], gv = g[row * 256 + e];
    float v = (sel == 0) ? qv : (sel == 1) ? gv : (sel == 2) ? fabsf(qv - gv) : qv * gv;
    feat2[idx] = v;
}

// ---------------- conv1d (VALID) + relu + maxpool over positions ----------------
// Input x viewed as [b][c=64][e=256]; conv runs over c with channels e.
template <int KW>
__global__ __launch_bounds__(64) void conv_pool_kernel(
    const float* __restrict__ x, const float* __restrict__ w,
    const float* __restrict__ wb, float* __restrict__ pooled, int fofs)
{
    __shared__ float xs[64 * 133];  // [c][e-half], stride 133 (odd vs 32 banks)
    const int tid = threadIdx.x;    // position p
    const int b = blockIdx.x >> 4, fg = blockIdx.x & 15;
    const int fbase = fg * 8;
    const int P = 64 - KW + 1;

    float acc[8];
#pragma unroll
    for (int f = 0; f < 8; ++f) acc[f] = wb[fbase + f];

    for (int half = 0; half < 2; ++half) {
        __syncthreads();
        for (int i = tid; i < 64 * 128; i += 64) {
            int cc = i >> 7, e = i & 127;
            xs[cc * 133 + e] = x[((size_t)b * 64 + cc) * 256 + half * 128 + e];
        }
        __syncthreads();
        for (int e = 0; e < 128; ++e) {
            float xv[KW];
#pragma unroll
            for (int i = 0; i < KW; ++i) {
                int rr = tid + i; if (rr > 63) rr = 63;  // clamp for invalid p (unused)
                xv[i] = xs[rr * 133 + e];
            }
#pragma unroll
            for (int f = 0; f < 8; ++f) {
                const float* wp = w + ((size_t)(fbase + f) * 256 + half * 128 + e) * KW;
                float s = 0.f;
#pragma unroll
                for (int i = 0; i < KW; ++i) s += xv[i] * wp[i];
                acc[f] += s;
            }
        }
    }

#pragma unroll
    for (int f = 0; f < 8; ++f) {
        float r = (tid < P) ? fmaxf(acc[f], 0.f) : 0.f;  // relu>=0 so 0 is neutral for max
        for (int off = 32; off; off >>= 1) r = fmaxf(r, __shfl_xor(r, off));
        if (tid == 0) pooled[b * 384 + fofs + fbase + f] = r;
    }
}

// ---------------- final FC: out[b][t] = cnn[b] . W_cnn[t] + b_cnn[t] ----------------
__global__ void final_kernel(const float* __restrict__ cnn, const float* __restrict__ Wc,
                             const float* __restrict__ bc, float* __restrict__ out)
{
    int o = threadIdx.x;
    if (o >= 320) return;
    int b = o / 40, t = o - b * 40;
    float s = bc[t];
    for (int i = 0; i < 384; ++i) s += cnn[b * 384 + i] * Wc[t * 384 + i];
    out[o] = s;
}

extern "C" void kernel_launch(void* const* d_in, const int* in_sizes, int n_in,
                              void* d_out, int out_size, void* d_ws, size_t ws_size,
                              hipStream_t stream)
{
    (void)in_sizes; (void)n_in; (void)out_size; (void)ws_size;
    const float* q    = (const float*)d_in[0];
    const float* ctx  = (const float*)d_in[1];
    const int*   mask = (const int*)d_in[2];
    const float* Wh   = (const float*)d_in[3];
    const float* bh   = (const float*)d_in[4];
    const float* Wv   = (const float*)d_in[5];
    const float* bv   = (const float*)d_in[6];
    const float* Wl   = (const float*)d_in[7];
    const float* bl   = (const float*)d_in[8];
    const float* cw0  = (const float*)d_in[9];
    const float* cb0  = (const float*)d_in[10];
    const float* cw1  = (const float*)d_in[11];
    const float* cb1  = (const float*)d_in[12];
    const float* cw2  = (const float*)d_in[13];
    const float* cb2  = (const float*)d_in[14];
    const float* Wc   = (const float*)d_in[15];
    const float* bc   = (const float*)d_in[16];

    float* ws    = (float*)d_ws;
    float* Apre  = ws;                    // 64*1024
    float* Bmat  = Apre  + 65536;         // 1024*1024
    float* g     = Bmat  + 1048576;       // 512*256
    float* feat2 = g     + 131072;        // 512*1024
    float* h2    = feat2 + 524288;        // 512*1024
    float* x     = h2    + 524288;        // 512*256
    float* cnn   = x     + 131072;        // 8*384
    // total ~2.43M floats (~9.7 MB) of d_ws

    dim3 blk(256);
    // Apre = q @ W1^T + b_hidden   (M=64, N=1024, K=256)
    gemm_tn_kernel<<<dim3(16, 1), blk, 0, stream>>>(q, 256, Wh, 1024, bh, Apre, 1024, 256, 0);
    // Bmat = ctx @ W2^T            (M=1024, N=1024, K=256)
    gemm_tn_kernel<<<dim3(16, 16), blk, 0, stream>>>(ctx, 256, Wh + 256, 1024, nullptr, Bmat, 1024, 256, 0);
    // fused pair-GEMM + softmax + g
    attn_kernel<<<512, blk, 0, stream>>>(q, ctx, mask, Wh, Wv, bv, Apre, Bmat, g);
    // h2 = tanh(feat2 @ Wh^T + bh); x = h2 @ Wl^T + bl
    feat2_kernel<<<2048, blk, 0, stream>>>(q, g, feat2);
    gemm_tn_kernel<<<dim3(16, 8), blk, 0, stream>>>(feat2, 1024, Wh, 1024, bh, h2, 1024, 1024, 1);
    gemm_tn_kernel<<<dim3(4, 8), blk, 0, stream>>>(h2, 1024, Wl, 1024, bl, x, 256, 1024, 0);
    // convs + pool
    conv_pool_kernel<5><<<128, 64, 0, stream>>>(x, cw0, cb0, cnn, 0);
    conv_pool_kernel<4><<<128, 64, 0, stream>>>(x, cw1, cb1, cnn, 128);
    conv_pool_kernel<3><<<128, 64, 0, stream>>>(x, cw2, cb2, cnn, 256);
    // final FC
    final_kernel<<<1, 320, 0, stream>>>(cnn, Wc, bc, (float*)d_out);
}

// Round 2
// 712.203 us; speedup vs baseline: 2.6208x; 2.6208x over previous
//
#include <hip/hip_runtime.h>
#include <math.h>

// Problem constants: B=8, C=64, T=128, E=256, 4E=1024, TYPE_NUM=40, NF=128
// Decomposition: h_pre[b,c,t,:] = Apre[c,:] + Bmat[b*T+t,:] + W34 @ [|q-ctx|; q*ctx]
//   Apre = q @ W1^T + b_hidden   (W1 = W_hidden[:,0:256])
//   Bmat = ctx @ W2^T            (W2 = W_hidden[:,256:512])
//   W34  = W_hidden[:,512:1024]  (pair terms, K=512) -> pre-converted to bf16
// attn kernel v2: bf16 MFMA 16x16x32 pair-GEMM (M=128 t x N=1024 j x K=512 per
// (b,c) block), fp32 epilogue tanh + Wv-dot + softmax + g = attn @ ctx.

typedef __bf16 bf16x8 __attribute__((ext_vector_type(8)));
typedef float  f32x4  __attribute__((ext_vector_type(4)));

// ---------------- generic fp32 tiled GEMM: C = act(A @ B^T + bias) ----------------
__global__ __launch_bounds__(256) void gemm_tn_kernel(
    const float* __restrict__ A, int lda,
    const float* __restrict__ B, int ldb,
    const float* __restrict__ bias,
    float* __restrict__ C, int ldc,
    int K, int act)
{
    __shared__ float As[16][68];
    __shared__ float Bs[16][68];
    const int tid = threadIdx.x;
    const int m0 = blockIdx.y * 64, n0 = blockIdx.x * 64;
    const int tm = tid >> 4, tn = tid & 15;
    const int lr = tid >> 2;
    const int lc = (tid & 3) * 4;

    float acc[4][4];
#pragma unroll
    for (int i = 0; i < 4; ++i)
#pragma unroll
        for (int j = 0; j < 4; ++j) acc[i][j] = 0.f;

    for (int k0 = 0; k0 < K; k0 += 16) {
        float4 av = *reinterpret_cast<const float4*>(A + (size_t)(m0 + lr) * lda + k0 + lc);
        float4 bv = *reinterpret_cast<const float4*>(B + (size_t)(n0 + lr) * ldb + k0 + lc);
        As[lc + 0][lr] = av.x; As[lc + 1][lr] = av.y; As[lc + 2][lr] = av.z; As[lc + 3][lr] = av.w;
        Bs[lc + 0][lr] = bv.x; Bs[lc + 1][lr] = bv.y; Bs[lc + 2][lr] = bv.z; Bs[lc + 3][lr] = bv.w;
        __syncthreads();
#pragma unroll
        for (int kk = 0; kk < 16; ++kk) {
            float4 a = *reinterpret_cast<const float4*>(&As[kk][tm * 4]);
            float4 b = *reinterpret_cast<const float4*>(&Bs[kk][tn * 4]);
            float ar[4] = {a.x, a.y, a.z, a.w};
            float br[4] = {b.x, b.y, b.z, b.w};
#pragma unroll
            for (int i = 0; i < 4; ++i)
#pragma unroll
                for (int j = 0; j < 4; ++j) acc[i][j] += ar[i] * br[j];
        }
        __syncthreads();
    }

#pragma unroll
    for (int i = 0; i < 4; ++i) {
        int m = m0 + tm * 4 + i;
        float vals[4];
#pragma unroll
        for (int j = 0; j < 4; ++j) {
            int n = n0 + tn * 4 + j;
            float v = acc[i][j];
            if (bias) v += bias[n];
            if (act) v = tanhf(v);
            vals[j] = v;
        }
        float4 o; o.x = vals[0]; o.y = vals[1]; o.z = vals[2]; o.w = vals[3];
        *reinterpret_cast<float4*>(C + (size_t)m * ldc + n0 + tn * 4) = o;
    }
}

// ---------------- prep: W34 fp32 -> bf16, k-contiguous [1024][512] ----------------
__global__ void cvt_w34_kernel(const float* __restrict__ Wh, __bf16* __restrict__ Whbf)
{
    int idx = blockIdx.x * 256 + threadIdx.x;   // < 1024*512
    int j = idx >> 9, k = idx & 511;
    Whbf[idx] = (__bf16)Wh[(size_t)j * 1024 + 512 + k];
}

// ---------------- fused bf16-MFMA pair-GEMM + tanh + W_v dot + softmax + g -------
// One block per (b,c). 256 threads = 4 waves. Block tile 128(t) x 256(j-chunk),
// wave tile 64 x 128 using 4x8 frags of 16x16x32 bf16 MFMA. K=512 staged in
// 64-wide LDS chunks, row stride 72 bf16 (144B -> only 2-way bank aliasing, free).
__global__ __launch_bounds__(256, 2) void attn_kernel(
    const float* __restrict__ q,     // [64][256]
    const float* __restrict__ ctx,   // [8][128][256]
    const int*   __restrict__ mask,  // [8][128]
    const __bf16* __restrict__ Whbf, // [1024][512] bf16 (pair half of W_hidden)
    const float* __restrict__ Wv,    // [1024]
    const float* __restrict__ bv,    // [1]
    const float* __restrict__ Apre,  // [64][1024]  (includes b_hidden)
    const float* __restrict__ Bmat,  // [1024][1024]
    float* __restrict__ g)           // [512][256]
{
    __shared__ __bf16 Us[128 * 72];   // [t][k-chunk], padded stride 72
    __shared__ __bf16 Ws[256 * 72];   // [j][k-chunk], padded stride 72
    __shared__ float qc[256];
    __shared__ float sc[128];
    __shared__ float red;

    const int tid = threadIdx.x;
    const int b = blockIdx.x >> 6, c = blockIdx.x & 63;
    const int wave = tid >> 6, lane = tid & 63;
    const int w0 = wave >> 1, w1 = wave & 1;      // t-half, j-half
    const int m0 = w0 * 64;
    const int l15 = lane & 15, quad = lane >> 4;

    qc[tid] = q[c * 256 + tid];
    if (tid < 128) sc[tid] = 0.f;
    __syncthreads();

    for (int nc = 0; nc < 4; ++nc) {              // N-chunks of 256
        f32x4 acc[4][8];
#pragma unroll
        for (int mi = 0; mi < 4; ++mi)
#pragma unroll
            for (int ni = 0; ni < 8; ++ni) acc[mi][ni] = (f32x4){0.f, 0.f, 0.f, 0.f};

        for (int k0 = 0; k0 < 512; k0 += 64) {    // K-chunks of 64
            __syncthreads();                       // protect prior chunk's reads
            // stage W tile: Ws[row][kk] = Whbf[nc*256+row][k0+kk], rows 0..255
#pragma unroll
            for (int it = 0; it < 8; ++it) {
                int idx = tid + it * 256;          // 2048 = 256 rows x 8 granules
                int row = idx >> 3, kg = idx & 7;
                int4 v = *reinterpret_cast<const int4*>(
                    Whbf + ((size_t)(nc * 256 + row) * 512 + k0 + kg * 8));
                *reinterpret_cast<int4*>(&Ws[row * 72 + kg * 8]) = v;
            }
            // stage U tile: Us[t][kk]; k<256 -> |q-ctx|, k>=256 -> q*ctx
            const int e0 = k0 & 255;
            const bool isabs = (k0 < 256);
#pragma unroll
            for (int it = 0; it < 4; ++it) {
                int idx = tid + it * 256;          // 1024 = 128 rows x 8 granules
                int t = idx >> 3, kg = idx & 7;
                int eb = e0 + kg * 8;
                const float* cp = ctx + (size_t)(b * 128 + t) * 256 + eb;
                float4 c0 = *reinterpret_cast<const float4*>(cp);
                float4 c1 = *reinterpret_cast<const float4*>(cp + 4);
                float cv[8] = {c0.x, c0.y, c0.z, c0.w, c1.x, c1.y, c1.z, c1.w};
                bf16x8 u;
#pragma unroll
                for (int i = 0; i < 8; ++i) {
                    float qv = qc[eb + i];
                    float x = isabs ? fabsf(qv - cv[i]) : qv * cv[i];
                    u[i] = (__bf16)x;
                }
                *reinterpret_cast<bf16x8*>(&Us[t * 72 + kg * 8]) = u;
            }
            __syncthreads();
            // MFMA: two 32-k steps per staged chunk
#pragma unroll
            for (int ks = 0; ks < 2; ++ks) {
                bf16x8 a[4], bf[8];
#pragma unroll
                for (int mi = 0; mi < 4; ++mi)
                    a[mi] = *reinterpret_cast<const bf16x8*>(
                        &Us[(m0 + mi * 16 + l15) * 72 + ks * 32 + quad * 8]);
#pragma unroll
                for (int ni = 0; ni < 8; ++ni)
                    bf[ni] = *reinterpret_cast<const bf16x8*>(
                        &Ws[(w1 * 128 + ni * 16 + l15) * 72 + ks * 32 + quad * 8]);
#pragma unroll
                for (int mi = 0; mi < 4; ++mi)
#pragma unroll
                    for (int ni = 0; ni < 8; ++ni)
                        acc[mi][ni] = __builtin_amdgcn_mfma_f32_16x16x32_bf16(
                            a[mi], bf[ni], acc[mi][ni], 0, 0, 0);
            }
        }

        // epilogue: h = tanh(acc + Apre + Bmat), partial score = h . Wv
        // C/D layout: col j = n-frag base + l15, rows t = m-frag base + quad*4 + r
        const int jcol = nc * 256 + w1 * 128 + l15;
        float av[8], wv[8];
#pragma unroll
        for (int ni = 0; ni < 8; ++ni) {
            av[ni] = Apre[c * 1024 + jcol + ni * 16];
            wv[ni] = Wv[jcol + ni * 16];
        }
#pragma unroll
        for (int mi = 0; mi < 4; ++mi) {
            const int tbase = m0 + mi * 16 + quad * 4;
            float p[4];
#pragma unroll
            for (int r = 0; r < 4; ++r) {
                const float* bm = Bmat + (size_t)(b * 128 + tbase + r) * 1024 + jcol;
                float s = 0.f;
#pragma unroll
                for (int ni = 0; ni < 8; ++ni)
                    s += tanhf(acc[mi][ni][r] + av[ni] + bm[ni * 16]) * wv[ni];
                p[r] = s;
            }
#pragma unroll
            for (int off = 1; off < 16; off <<= 1)
#pragma unroll
                for (int r = 0; r < 4; ++r) p[r] += __shfl_xor(p[r], off, 16);
            if (l15 == 0) {
#pragma unroll
                for (int r = 0; r < 4; ++r) atomicAdd(&sc[tbase + r], p[r]);
            }
        }
    }
    __syncthreads();

    // mask + b_v, then softmax over t
    if (tid < 128) {
        float s = sc[tid] + bv[0];
        if (mask[b * 128 + tid] < 1) s = -1e10f;
        sc[tid] = s;
    }
    __syncthreads();
    if (tid < 64) {
        float m = fmaxf(sc[tid], sc[tid + 64]);
        for (int off = 32; off; off >>= 1) m = fmaxf(m, __shfl_xor(m, off, 64));
        if (tid == 0) red = m;
    }
    __syncthreads();
    const float mx = red;
    if (tid < 128) sc[tid] = expf(sc[tid] - mx);
    __syncthreads();
    if (tid < 64) {
        float s = sc[tid] + sc[tid + 64];
        for (int off = 32; off; off >>= 1) s += __shfl_xor(s, off, 64);
        if (tid == 0) red = s;
    }
    __syncthreads();
    const float inv = 1.f / red;

    // g[b,c,e] = sum_t attn[t] * ctx[b,t,e]
    float gv = 0.f;
    for (int t = 0; t < 128; ++t) gv += sc[t] * ctx[(size_t)(b * 128 + t) * 256 + tid];
    g[(size_t)blockIdx.x * 256 + tid] = gv * inv;
}

// ---------------- build feat2 = [q, g, |q-g|, q*g] for the h2 GEMM ----------------
__global__ void feat2_kernel(const float* __restrict__ q, const float* __restrict__ g,
                             float* __restrict__ feat2)
{
    int idx = blockIdx.x * 256 + threadIdx.x;  // < 512*1024
    int row = idx >> 10, col = idx & 1023;
    int c = row & 63;
    int e = col & 255, sel = col >> 8;
    float qv = q[c * 256 + e], gv = g[row * 256 + e];
    float v = (sel == 0) ? qv : (sel == 1) ? gv : (sel == 2) ? fabsf(qv - gv) : qv * gv;
    feat2[idx] = v;
}

// ---------------- conv1d (VALID) + relu + maxpool over positions ----------------
template <int KW>
__global__ __launch_bounds__(64) void conv_pool_kernel(
    const float* __restrict__ x, const float* __restrict__ w,
    const float* __restrict__ wb, float* __restrict__ pooled, int fofs)
{
    __shared__ float xs[64 * 133];
    const int tid = threadIdx.x;
    const int b = blockIdx.x >> 4, fg = blockIdx.x & 15;
    const int fbase = fg * 8;
    const int P = 64 - KW + 1;

    float acc[8];
#pragma unroll
    for (int f = 0; f < 8; ++f) acc[f] = wb[fbase + f];

    for (int half = 0; half < 2; ++half) {
        __syncthreads();
        for (int i = tid; i < 64 * 128; i += 64) {
            int cc = i >> 7, e = i & 127;
            xs[cc * 133 + e] = x[((size_t)b * 64 + cc) * 256 + half * 128 + e];
        }
        __syncthreads();
        for (int e = 0; e < 128; ++e) {
            float xv[KW];
#pragma unroll
            for (int i = 0; i < KW; ++i) {
                int rr = tid + i; if (rr > 63) rr = 63;
                xv[i] = xs[rr * 133 + e];
            }
#pragma unroll
            for (int f = 0; f < 8; ++f) {
                const float* wp = w + ((size_t)(fbase + f) * 256 + half * 128 + e) * KW;
                float s = 0.f;
#pragma unroll
                for (int i = 0; i < KW; ++i) s += xv[i] * wp[i];
                acc[f] += s;
            }
        }
    }

#pragma unroll
    for (int f = 0; f < 8; ++f) {
        float r = (tid < P) ? fmaxf(acc[f], 0.f) : 0.f;
        for (int off = 32; off; off >>= 1) r = fmaxf(r, __shfl_xor(r, off));
        if (tid == 0) pooled[b * 384 + fofs + fbase + f] = r;
    }
}

// ---------------- final FC ----------------
__global__ void final_kernel(const float* __restrict__ cnn, const float* __restrict__ Wc,
                             const float* __restrict__ bc, float* __restrict__ out)
{
    int o = threadIdx.x;
    if (o >= 320) return;
    int b = o / 40, t = o - b * 40;
    float s = bc[t];
    for (int i = 0; i < 384; ++i) s += cnn[b * 384 + i] * Wc[t * 384 + i];
    out[o] = s;
}

extern "C" void kernel_launch(void* const* d_in, const int* in_sizes, int n_in,
                              void* d_out, int out_size, void* d_ws, size_t ws_size,
                              hipStream_t stream)
{
    (void)in_sizes; (void)n_in; (void)out_size; (void)ws_size;
    const float* q    = (const float*)d_in[0];
    const float* ctx  = (const float*)d_in[1];
    const int*   mask = (const int*)d_in[2];
    const float* Wh   = (const float*)d_in[3];
    const float* bh   = (const float*)d_in[4];
    const float* Wv   = (const float*)d_in[5];
    const float* bv   = (const float*)d_in[6];
    const float* Wl   = (const float*)d_in[7];
    const float* bl   = (const float*)d_in[8];
    const float* cw0  = (const float*)d_in[9];
    const float* cb0  = (const float*)d_in[10];
    const float* cw1  = (const float*)d_in[11];
    const float* cb1  = (const float*)d_in[12];
    const float* cw2  = (const float*)d_in[13];
    const float* cb2  = (const float*)d_in[14];
    const float* Wc   = (const float*)d_in[15];
    const float* bc   = (const float*)d_in[16];

    float* ws    = (float*)d_ws;
    float* Apre  = ws;                    // 64*1024
    float* Bmat  = Apre  + 65536;         // 1024*1024
    float* g     = Bmat  + 1048576;       // 512*256
    float* feat2 = g     + 131072;        // 512*1024
    float* h2    = feat2 + 524288;        // 512*1024
    float* x     = h2    + 524288;        // 512*256
    float* cnn   = x     + 131072;        // 8*384
    __bf16* Whbf = (__bf16*)(cnn + 3072); // 1024*512 bf16 (1MB), 16B-aligned
    // total ~10.8 MB of d_ws

    dim3 blk(256);
    // prep: pair half of W_hidden -> bf16
    cvt_w34_kernel<<<2048, blk, 0, stream>>>(Wh, Whbf);
    // Apre = q @ W1^T + b_hidden   (M=64, N=1024, K=256)
    gemm_tn_kernel<<<dim3(16, 1), blk, 0, stream>>>(q, 256, Wh, 1024, bh, Apre, 1024, 256, 0);
    // Bmat = ctx @ W2^T            (M=1024, N=1024, K=256)
    gemm_tn_kernel<<<dim3(16, 16), blk, 0, stream>>>(ctx, 256, Wh + 256, 1024, nullptr, Bmat, 1024, 256, 0);
    // fused MFMA pair-GEMM + softmax + g
    attn_kernel<<<512, blk, 0, stream>>>(q, ctx, mask, Whbf, Wv, bv, Apre, Bmat, g);
    // h2 = tanh(feat2 @ Wh^T + bh); x = h2 @ Wl^T + bl
    feat2_kernel<<<2048, blk, 0, stream>>>(q, g, feat2);
    gemm_tn_kernel<<<dim3(16, 8), blk, 0, stream>>>(feat2, 1024, Wh, 1024, bh, h2, 1024, 1024, 1);
    gemm_tn_kernel<<<dim3(4, 8), blk, 0, stream>>>(h2, 1024, Wl, 1024, bl, x, 256, 1024, 0);
    // convs + pool
    conv_pool_kernel<5><<<128, 64, 0, stream>>>(x, cw0, cb0, cnn, 0);
    conv_pool_kernel<4><<<128, 64, 0, stream>>>(x, cw1, cb1, cnn, 128);
    conv_pool_kernel<3><<<128, 64, 0, stream>>>(x, cw2, cb2, cnn, 256);
    // final FC
    final_kernel<<<1, 320, 0, stream>>>(cnn, Wc, bc, (float*)d_out);
}

// Round 3
// 376.378 us; speedup vs baseline: 4.9592x; 1.8923x over previous
//
#include <hip/hip_runtime.h>
#include <math.h>

// B=8, C=64, T=128, E=256, 4E=1024, TYPE_NUM=40, NF=128
// h_pre[b,c,t,:] = Apre[c,:] + [ctx, |q-ctx|, q*ctx] @ Wh[:,256:1024]^T   (K=768 MFMA)
//   Apre = q @ W1^T + b_hidden (fp32, exact)
// attn v3: bf16 MFMA 16x16x32, fast tanh, no Bmat. h2/x chain via bf16 MFMA GEMM.

typedef __bf16 bf16x8 __attribute__((ext_vector_type(8)));
typedef float  f32x4  __attribute__((ext_vector_type(4)));

__device__ __forceinline__ float ftanh(float v) {
    // tanh(x) = 1 - 2/(e^{2x}+1); branchless, handles +-inf correctly
    float t = __expf(2.f * v);
    return 1.f - 2.f * __builtin_amdgcn_rcpf(t + 1.f);
}

// ---------------- fp32 tiled GEMM (only for Apre: M=64,N=1024,K=256) ----------------
__global__ __launch_bounds__(256) void gemm_tn_kernel(
    const float* __restrict__ A, int lda,
    const float* __restrict__ B, int ldb,
    const float* __restrict__ bias,
    float* __restrict__ C, int ldc,
    int K, int act)
{
    __shared__ float As[16][68];
    __shared__ float Bs[16][68];
    const int tid = threadIdx.x;
    const int m0 = blockIdx.y * 64, n0 = blockIdx.x * 64;
    const int tm = tid >> 4, tn = tid & 15;
    const int lr = tid >> 2;
    const int lc = (tid & 3) * 4;

    float acc[4][4];
#pragma unroll
    for (int i = 0; i < 4; ++i)
#pragma unroll
        for (int j = 0; j < 4; ++j) acc[i][j] = 0.f;

    for (int k0 = 0; k0 < K; k0 += 16) {
        float4 av = *reinterpret_cast<const float4*>(A + (size_t)(m0 + lr) * lda + k0 + lc);
        float4 bv = *reinterpret_cast<const float4*>(B + (size_t)(n0 + lr) * ldb + k0 + lc);
        As[lc + 0][lr] = av.x; As[lc + 1][lr] = av.y; As[lc + 2][lr] = av.z; As[lc + 3][lr] = av.w;
        Bs[lc + 0][lr] = bv.x; Bs[lc + 1][lr] = bv.y; Bs[lc + 2][lr] = bv.z; Bs[lc + 3][lr] = bv.w;
        __syncthreads();
#pragma unroll
        for (int kk = 0; kk < 16; ++kk) {
            float4 a = *reinterpret_cast<const float4*>(&As[kk][tm * 4]);
            float4 b = *reinterpret_cast<const float4*>(&Bs[kk][tn * 4]);
            float ar[4] = {a.x, a.y, a.z, a.w};
            float br[4] = {b.x, b.y, b.z, b.w};
#pragma unroll
            for (int i = 0; i < 4; ++i)
#pragma unroll
                for (int j = 0; j < 4; ++j) acc[i][j] += ar[i] * br[j];
        }
        __syncthreads();
    }

#pragma unroll
    for (int i = 0; i < 4; ++i) {
        int m = m0 + tm * 4 + i;
        float vals[4];
#pragma unroll
        for (int j = 0; j < 4; ++j) {
            int n = n0 + tn * 4 + j;
            float v = acc[i][j];
            if (bias) v += bias[n];
            if (act) v = ftanh(v);
            vals[j] = v;
        }
        float4 o; o.x = vals[0]; o.y = vals[1]; o.z = vals[2]; o.w = vals[3];
        *reinterpret_cast<float4*>(C + (size_t)m * ldc + n0 + tn * 4) = o;
    }
}

// ---------------- one-shot fp32 -> bf16 conversions ----------------
// Whbf [1024][1024] <- W_hidden, Wlbf [256][1024] <- W_lin, ctxbf [1024][256] <- ctx
__global__ void cvt_kernel(const float* __restrict__ Wh, const float* __restrict__ Wl,
                           const float* __restrict__ ctx,
                           __bf16* __restrict__ Whbf, __bf16* __restrict__ Wlbf,
                           __bf16* __restrict__ ctxbf)
{
    int idx = blockIdx.x * 256 + threadIdx.x;   // < 1572864
    if (idx < 1048576) Whbf[idx] = (__bf16)Wh[idx];
    else if (idx < 1310720) Wlbf[idx - 1048576] = (__bf16)Wl[idx - 1048576];
    else ctxbf[idx - 1310720] = (__bf16)ctx[idx - 1310720];
}

// ---------------- fused bf16-MFMA attn: K=768 pair-GEMM + tanh + Wv + softmax + g ---
// One block per (b,c). 4 waves, block tile 128t x 256j per nc (4 chunks),
// wave tile 64x128 (4x8 frags of 16x16x32). K regions: [0,256)=ctx,
// [256,512)=|q-ctx|, [512,768)=q*ctx, pairing Wh cols 256..1023.
__global__ __launch_bounds__(256, 2) void attn_kernel(
    const float* __restrict__ q,      // [64][256]
    const float* __restrict__ ctx,    // [8][128][256] fp32
    const __bf16* __restrict__ ctxbf, // [1024][256] bf16
    const int*   __restrict__ mask,   // [8][128]
    const __bf16* __restrict__ Whbf,  // [1024][1024] bf16
    const float* __restrict__ Wv,     // [1024]
    const float* __restrict__ bv,     // [1]
    const float* __restrict__ Apre,   // [64][1024] (includes b_hidden)
    float* __restrict__ g)            // [512][256]
{
    __shared__ __bf16 Us[128 * 72];
    __shared__ __bf16 Ws[256 * 72];
    __shared__ float qc[256];
    __shared__ float sc[128];
    __shared__ float red;

    const int tid = threadIdx.x;
    const int b = blockIdx.x >> 6, c = blockIdx.x & 63;
    const int wave = tid >> 6, lane = tid & 63;
    const int w0 = wave >> 1, w1 = wave & 1;
    const int m0 = w0 * 64;
    const int l15 = lane & 15, quad = lane >> 4;

    qc[tid] = q[c * 256 + tid];
    if (tid < 128) sc[tid] = 0.f;
    __syncthreads();

    for (int nc = 0; nc < 4; ++nc) {
        f32x4 acc[4][8];
#pragma unroll
        for (int mi = 0; mi < 4; ++mi)
#pragma unroll
            for (int ni = 0; ni < 8; ++ni) acc[mi][ni] = (f32x4){0.f, 0.f, 0.f, 0.f};

        for (int kc = 0; kc < 12; ++kc) {          // K-chunks of 64 (K=768)
            __syncthreads();
            // stage W tile: Ws[row][kk] = Whbf[nc*256+row][256 + kc*64 + kk]
#pragma unroll
            for (int it = 0; it < 8; ++it) {
                int idx = tid + it * 256;           // 2048 granules
                int row = idx >> 3, kg = idx & 7;
                int4 v = *reinterpret_cast<const int4*>(
                    Whbf + ((size_t)(nc * 256 + row) * 1024 + 256 + kc * 64 + kg * 8));
                *reinterpret_cast<int4*>(&Ws[row * 72 + kg * 8]) = v;
            }
            // stage U tile (region uniform per kc)
            const int region = kc >> 2;             // 0: ctx copy, 1: abs, 2: mul
            const int e0 = (kc & 3) * 64;
            if (region == 0) {
#pragma unroll
                for (int it = 0; it < 4; ++it) {
                    int idx = tid + it * 256;       // 1024 granules
                    int t = idx >> 3, kg = idx & 7;
                    int4 v = *reinterpret_cast<const int4*>(
                        ctxbf + (size_t)(b * 128 + t) * 256 + e0 + kg * 8);
                    *reinterpret_cast<int4*>(&Us[t * 72 + kg * 8]) = v;
                }
            } else {
                const bool isabs = (region == 1);
#pragma unroll
                for (int it = 0; it < 4; ++it) {
                    int idx = tid + it * 256;
                    int t = idx >> 3, kg = idx & 7;
                    int eb = e0 + kg * 8;
                    const float* cp = ctx + (size_t)(b * 128 + t) * 256 + eb;
                    float4 c0 = *reinterpret_cast<const float4*>(cp);
                    float4 c1 = *reinterpret_cast<const float4*>(cp + 4);
                    float cv[8] = {c0.x, c0.y, c0.z, c0.w, c1.x, c1.y, c1.z, c1.w};
                    bf16x8 u;
#pragma unroll
                    for (int i = 0; i < 8; ++i) {
                        float qv = qc[eb + i];
                        float x = isabs ? fabsf(qv - cv[i]) : qv * cv[i];
                        u[i] = (__bf16)x;
                    }
                    *reinterpret_cast<bf16x8*>(&Us[t * 72 + kg * 8]) = u;
                }
            }
            __syncthreads();
#pragma unroll
            for (int ks = 0; ks < 2; ++ks) {
                bf16x8 a[4], bf[8];
#pragma unroll
                for (int mi = 0; mi < 4; ++mi)
                    a[mi] = *reinterpret_cast<const bf16x8*>(
                        &Us[(m0 + mi * 16 + l15) * 72 + ks * 32 + quad * 8]);
#pragma unroll
                for (int ni = 0; ni < 8; ++ni)
                    bf[ni] = *reinterpret_cast<const bf16x8*>(
                        &Ws[(w1 * 128 + ni * 16 + l15) * 72 + ks * 32 + quad * 8]);
#pragma unroll
                for (int mi = 0; mi < 4; ++mi)
#pragma unroll
                    for (int ni = 0; ni < 8; ++ni)
                        acc[mi][ni] = __builtin_amdgcn_mfma_f32_16x16x32_bf16(
                            a[mi], bf[ni], acc[mi][ni], 0, 0, 0);
            }
        }

        // epilogue: h = ftanh(acc + Apre), partial score = h . Wv
        const int jcol = nc * 256 + w1 * 128 + l15;
        float av[8], wv[8];
#pragma unroll
        for (int ni = 0; ni < 8; ++ni) {
            av[ni] = Apre[c * 1024 + jcol + ni * 16];
            wv[ni] = Wv[jcol + ni * 16];
        }
#pragma unroll
        for (int mi = 0; mi < 4; ++mi) {
            const int tbase = m0 + mi * 16 + quad * 4;
            float p[4];
#pragma unroll
            for (int r = 0; r < 4; ++r) {
                float s = 0.f;
#pragma unroll
                for (int ni = 0; ni < 8; ++ni)
                    s += ftanh(acc[mi][ni][r] + av[ni]) * wv[ni];
                p[r] = s;
            }
#pragma unroll
            for (int off = 1; off < 16; off <<= 1)
#pragma unroll
                for (int r = 0; r < 4; ++r) p[r] += __shfl_xor(p[r], off, 16);
            if (l15 == 0) {
#pragma unroll
                for (int r = 0; r < 4; ++r) atomicAdd(&sc[tbase + r], p[r]);
            }
        }
    }
    __syncthreads();

    // mask + b_v, softmax over t
    if (tid < 128) {
        float s = sc[tid] + bv[0];
        if (mask[b * 128 + tid] < 1) s = -1e10f;
        sc[tid] = s;
    }
    __syncthreads();
    if (tid < 64) {
        float m = fmaxf(sc[tid], sc[tid + 64]);
        for (int off = 32; off; off >>= 1) m = fmaxf(m, __shfl_xor(m, off, 64));
        if (tid == 0) red = m;
    }
    __syncthreads();
    const float mx = red;
    if (tid < 128) sc[tid] = __expf(sc[tid] - mx);
    __syncthreads();
    if (tid < 64) {
        float s = sc[tid] + sc[tid + 64];
        for (int off = 32; off; off >>= 1) s += __shfl_xor(s, off, 64);
        if (tid == 0) red = s;
    }
    __syncthreads();
    const float inv = 1.f / red;

    float gv = 0.f;
    for (int t = 0; t < 128; ++t) gv += sc[t] * ctx[(size_t)(b * 128 + t) * 256 + tid];
    g[(size_t)blockIdx.x * 256 + tid] = gv * inv;
}

// ---------------- feat2 = [q, g, |q-g|, q*g] in bf16 ----------------
__global__ void feat2_kernel(const float* __restrict__ q, const float* __restrict__ g,
                             __bf16* __restrict__ feat2)
{
    int idx = blockIdx.x * 256 + threadIdx.x;  // < 512*1024
    int row = idx >> 10, col = idx & 1023;
    int c = row & 63;
    int e = col & 255, sel = col >> 8;
    float qv = q[c * 256 + e], gv = g[row * 256 + e];
    float v = (sel == 0) ? qv : (sel == 1) ? gv : (sel == 2) ? fabsf(qv - gv) : qv * gv;
    feat2[idx] = (__bf16)v;
}

// ---------------- bf16 MFMA GEMM: C = act(A @ B^T + bias), 64x64 tile ----------------
template <int ACT, int OUTBF>
__global__ __launch_bounds__(256) void mfma_gemm_kernel(
    const __bf16* __restrict__ A, const __bf16* __restrict__ B,
    const float* __restrict__ bias, void* __restrict__ Cout,
    int K, int ldc)
{
    __shared__ __bf16 As[64 * 72];
    __shared__ __bf16 Bs[64 * 72];
    const int tid = threadIdx.x;
    const int wave = tid >> 6, lane = tid & 63;
    const int w0 = wave >> 1, w1 = wave & 1;
    const int l15 = lane & 15, quad = lane >> 4;
    const int m0 = blockIdx.y * 64, n0 = blockIdx.x * 64;

    f32x4 acc[2][2];
#pragma unroll
    for (int mi = 0; mi < 2; ++mi)
#pragma unroll
        for (int ni = 0; ni < 2; ++ni) acc[mi][ni] = (f32x4){0.f, 0.f, 0.f, 0.f};

    for (int k0 = 0; k0 < K; k0 += 64) {
        __syncthreads();
#pragma unroll
        for (int it = 0; it < 2; ++it) {
            int idx = tid + it * 256;        // 512 granules each
            int row = idx >> 3, kg = idx & 7;
            int4 va = *reinterpret_cast<const int4*>(A + (size_t)(m0 + row) * K + k0 + kg * 8);
            *reinterpret_cast<int4*>(&As[row * 72 + kg * 8]) = va;
            int4 vb = *reinterpret_cast<const int4*>(B + (size_t)(n0 + row) * K + k0 + kg * 8);
            *reinterpret_cast<int4*>(&Bs[row * 72 + kg * 8]) = vb;
        }
        __syncthreads();
#pragma unroll
        for (int ks = 0; ks < 2; ++ks) {
            bf16x8 a[2], bb[2];
#pragma unroll
            for (int mi = 0; mi < 2; ++mi)
                a[mi] = *reinterpret_cast<const bf16x8*>(
                    &As[(w0 * 32 + mi * 16 + l15) * 72 + ks * 32 + quad * 8]);
#pragma unroll
            for (int ni = 0; ni < 2; ++ni)
                bb[ni] = *reinterpret_cast<const bf16x8*>(
                    &Bs[(w1 * 32 + ni * 16 + l15) * 72 + ks * 32 + quad * 8]);
#pragma unroll
            for (int mi = 0; mi < 2; ++mi)
#pragma unroll
                for (int ni = 0; ni < 2; ++ni)
                    acc[mi][ni] = __builtin_amdgcn_mfma_f32_16x16x32_bf16(
                        a[mi], bb[ni], acc[mi][ni], 0, 0, 0);
        }
    }

#pragma unroll
    for (int mi = 0; mi < 2; ++mi)
#pragma unroll
        for (int ni = 0; ni < 2; ++ni) {
            int col = n0 + w1 * 32 + ni * 16 + l15;
            float bsv = bias ? bias[col] : 0.f;
#pragma unroll
            for (int r = 0; r < 4; ++r) {
                int row = m0 + w0 * 32 + mi * 16 + quad * 4 + r;
                float v = acc[mi][ni][r] + bsv;
                if (ACT) v = ftanh(v);
                if (OUTBF) ((__bf16*)Cout)[(size_t)row * ldc + col] = (__bf16)v;
                else       ((float*)Cout)[(size_t)row * ldc + col] = v;
            }
        }
}

// ---------------- merged conv1d + relu + maxpool (3 widths in one launch) ----------
template <int KW>
__device__ __forceinline__ void conv_impl(
    const float* __restrict__ x, const float* __restrict__ w,
    const float* __restrict__ wb, float* __restrict__ pooled,
    int fofs, int b, int fg, int tid, float* xs)
{
    const int fbase = fg * 8;
    const int P = 64 - KW + 1;

    float acc[8];
#pragma unroll
    for (int f = 0; f < 8; ++f) acc[f] = wb[fbase + f];

    for (int half = 0; half < 2; ++half) {
        __syncthreads();
        for (int i = tid; i < 64 * 128; i += 64) {
            int cc = i >> 7, e = i & 127;
            xs[cc * 133 + e] = x[((size_t)b * 64 + cc) * 256 + half * 128 + e];
        }
        __syncthreads();
        for (int e = 0; e < 128; ++e) {
            float xv[KW];
#pragma unroll
            for (int i = 0; i < KW; ++i) {
                int rr = tid + i; if (rr > 63) rr = 63;
                xv[i] = xs[rr * 133 + e];
            }
#pragma unroll
            for (int f = 0; f < 8; ++f) {
                const float* wp = w + ((size_t)(fbase + f) * 256 + half * 128 + e) * KW;
                float s = 0.f;
#pragma unroll
                for (int i = 0; i < KW; ++i) s += xv[i] * wp[i];
                acc[f] += s;
            }
        }
    }

#pragma unroll
    for (int f = 0; f < 8; ++f) {
        float r = (tid < P) ? fmaxf(acc[f], 0.f) : 0.f;
        for (int off = 32; off; off >>= 1) r = fmaxf(r, __shfl_xor(r, off));
        if (tid == 0) pooled[b * 384 + fofs + fbase + f] = r;
    }
}

__global__ __launch_bounds__(64) void conv_pool_all(
    const float* __restrict__ x,
    const float* __restrict__ w0, const float* __restrict__ b0,
    const float* __restrict__ w1, const float* __restrict__ b1,
    const float* __restrict__ w2, const float* __restrict__ b2,
    float* __restrict__ pooled)
{
    __shared__ float xs[64 * 133];
    const int bid = blockIdx.x;          // 0..383
    const int kwt = bid >> 7, rem = bid & 127;
    const int b = rem >> 4, fg = rem & 15;
    const int tid = threadIdx.x;
    if (kwt == 0)      conv_impl<5>(x, w0, b0, pooled, 0,   b, fg, tid, xs);
    else if (kwt == 1) conv_impl<4>(x, w1, b1, pooled, 128, b, fg, tid, xs);
    else               conv_impl<3>(x, w2, b2, pooled, 256, b, fg, tid, xs);
}

// ---------------- final FC ----------------
__global__ void final_kernel(const float* __restrict__ cnn, const float* __restrict__ Wc,
                             const float* __restrict__ bc, float* __restrict__ out)
{
    int o = threadIdx.x;
    if (o >= 320) return;
    int b = o / 40, t = o - b * 40;
    float s = bc[t];
    for (int i = 0; i < 384; ++i) s += cnn[b * 384 + i] * Wc[t * 384 + i];
    out[o] = s;
}

extern "C" void kernel_launch(void* const* d_in, const int* in_sizes, int n_in,
                              void* d_out, int out_size, void* d_ws, size_t ws_size,
                              hipStream_t stream)
{
    (void)in_sizes; (void)n_in; (void)out_size; (void)ws_size;
    const float* q    = (const float*)d_in[0];
    const float* ctx  = (const float*)d_in[1];
    const int*   mask = (const int*)d_in[2];
    const float* Wh   = (const float*)d_in[3];
    const float* bh   = (const float*)d_in[4];
    const float* Wv   = (const float*)d_in[5];
    const float* bv   = (const float*)d_in[6];
    const float* Wl   = (const float*)d_in[7];
    const float* bl   = (const float*)d_in[8];
    const float* cw0  = (const float*)d_in[9];
    const float* cb0  = (const float*)d_in[10];
    const float* cw1  = (const float*)d_in[11];
    const float* cb1  = (const float*)d_in[12];
    const float* cw2  = (const float*)d_in[13];
    const float* cb2  = (const float*)d_in[14];
    const float* Wc   = (const float*)d_in[15];
    const float* bc   = (const float*)d_in[16];

    float* ws   = (float*)d_ws;
    float* Apre = ws;                 // 65536
    float* g    = ws + 65536;         // 131072
    float* x    = ws + 196608;        // 131072
    float* cnn  = ws + 327680;        // 3072
    __bf16* bfb   = (__bf16*)(ws + 330752);   // 16B-aligned
    __bf16* Whbf  = bfb;                      // 1048576
    __bf16* Wlbf  = bfb + 1048576;            // 262144
    __bf16* ctxbf = bfb + 1310720;            // 262144
    __bf16* feat2b= bfb + 1572864;            // 524288
    __bf16* h2b   = bfb + 2097152;            // 524288
    // total ~6.6 MB of d_ws

    dim3 blk(256);
    cvt_kernel<<<6144, blk, 0, stream>>>(Wh, Wl, ctx, Whbf, Wlbf, ctxbf);
    // Apre = q @ W1^T + b_hidden (fp32 exact), W1 = Wh[:,0:256]
    gemm_tn_kernel<<<dim3(16, 1), blk, 0, stream>>>(q, 256, Wh, 1024, bh, Apre, 1024, 256, 0);
    // fused MFMA attn (K=768, ctx folded)
    attn_kernel<<<512, blk, 0, stream>>>(q, ctx, ctxbf, mask, Whbf, Wv, bv, Apre, g);
    // feat2 (bf16), h2 = tanh(feat2 @ Wh^T + bh) bf16, x = h2 @ Wl^T + bl fp32
    feat2_kernel<<<2048, blk, 0, stream>>>(q, g, feat2b);
    mfma_gemm_kernel<1, 1><<<dim3(16, 8), blk, 0, stream>>>(feat2b, Whbf, bh, h2b, 1024, 1024);
    mfma_gemm_kernel<0, 0><<<dim3(4, 8), blk, 0, stream>>>(h2b, Wlbf, bl, x, 1024, 256);
    // convs + pool (merged) and final FC
    conv_pool_all<<<384, 64, 0, stream>>>(x, cw0, cb0, cw1, cb1, cw2, cb2, cnn);
    final_kernel<<<1, 320, 0, stream>>>(cnn, Wc, bc, (float*)d_out);
}